// Round 1
// baseline (95.614 us; speedup 1.0000x reference)
//
#include <hip/hip_runtime.h>

#define NPTS   1024   // points per batch
#define NGRID  4096   // 64x64 grid
#define NBATCH 16
#define NCH    8      // feature channels in Y

// One block = one (batch, 256-grid-point chunk). 256 blocks x 256 threads.
// X,Y for the batch staged in LDS; inner n-loop reads are wave-broadcast
// (all lanes read the same address -> conflict-free).
__global__ __launch_bounds__(256) void rkhs_embed_kernel(
    const float* __restrict__ X,   // (16,1024,2)
    const float* __restrict__ Y,   // (16,1024,8)
    float* __restrict__ out)       // [grid: 8192 floats][Y_grid: 16*4096*9]
{
    __shared__ float sX[NPTS * 2];     // 8 KB
    __shared__ float sY[NPTS * NCH];   // 32 KB

    const int b     = blockIdx.x >> 4;   // 0..15
    const int chunk = blockIdx.x & 15;   // 0..15
    const int tid   = threadIdx.x;       // 0..255

    // Cooperative staging, float4-vectorized, fully coalesced.
    const float4* Xg  = (const float4*)(X + (size_t)b * NPTS * 2);
    float4*       sX4 = (float4*)sX;
#pragma unroll
    for (int i = 0; i < (NPTS * 2 / 4) / 256; ++i)    // 2 iters
        sX4[tid + 256 * i] = Xg[tid + 256 * i];

    const float4* Yg  = (const float4*)(Y + (size_t)b * NPTS * NCH);
    float4*       sY4 = (float4*)sY;
#pragma unroll
    for (int i = 0; i < (NPTS * NCH / 4) / 256; ++i)  // 8 iters
        sY4[tid + 256 * i] = Yg[tid + 256 * i];

    __syncthreads();

    const int   m    = chunk * 256 + tid;   // grid point index, 0..4095
    const float step = 6.0f / 63.0f;        // linspace(-3,3,64) step
    const float gx   = -3.0f + (float)(m >> 6) * step;
    const float gy   = -3.0f + (float)(m & 63) * step;

    // Output 0: the grid itself (written once, by the b==0 blocks).
    if (b == 0) {
        out[2 * m]     = gx;
        out[2 * m + 1] = gy;
    }

    float acc0 = 0.0f;      // density = sum of weights
    float acc[NCH] = {0.0f, 0.0f, 0.0f, 0.0f, 0.0f, 0.0f, 0.0f, 0.0f};

    const float2* sX2 = (const float2*)sX;

#pragma unroll 4
    for (int n = 0; n < NPTS; ++n) {
        const float2 xn = sX2[n];                 // broadcast LDS read
        const float dx = gx - xn.x;
        const float dy = gy - xn.y;
        const float d2 = fmaf(dx, dx, dy * dy);
        // K = exp(-d2 / (2*0.5^2)) = exp(-2*d2); __expf -> v_exp_f32
        const float w = __expf(-2.0f * d2);

        const float4 y0 = sY4[2 * n];             // broadcast LDS reads
        const float4 y1 = sY4[2 * n + 1];

        acc0   += w;
        acc[0]  = fmaf(w, y0.x, acc[0]);
        acc[1]  = fmaf(w, y0.y, acc[1]);
        acc[2]  = fmaf(w, y0.z, acc[2]);
        acc[3]  = fmaf(w, y0.w, acc[3]);
        acc[4]  = fmaf(w, y1.x, acc[4]);
        acc[5]  = fmaf(w, y1.y, acc[5]);
        acc[6]  = fmaf(w, y1.z, acc[6]);
        acc[7]  = fmaf(w, y1.w, acc[7]);
    }

    const float inv = 1.0f / (acc0 + 1e-6f);
    float* o = out + (size_t)NGRID * 2 + ((size_t)b * NGRID + m) * 9;
    o[0] = acc0;
#pragma unroll
    for (int c = 0; c < NCH; ++c)
        o[1 + c] = acc[c] * inv;
}

extern "C" void kernel_launch(void* const* d_in, const int* in_sizes, int n_in,
                              void* d_out, int out_size, void* d_ws, size_t ws_size,
                              hipStream_t stream) {
    const float* X = (const float*)d_in[0];   // (16,1024,2) fp32
    const float* Y = (const float*)d_in[1];   // (16,1024,8) fp32
    float* out = (float*)d_out;               // 8192 + 589824 floats

    dim3 grid(NBATCH * (NGRID / 256));        // 256 blocks
    dim3 block(256);
    rkhs_embed_kernel<<<grid, block, 0, stream>>>(X, Y, out);
}

// Round 3
// 80.502 us; speedup vs baseline: 1.1877x; 1.1877x over previous
//
#include <hip/hip_runtime.h>

#define NPTS   1024   // points per batch
#define NGRID  4096   // 64x64 grid
#define NBATCH 16
#define NCH    8      // feature channels in Y
#define NSEG   8      // n-loop split factor (waves per block)
#define GPT    64     // grid points per block
#define SEGLEN (NPTS / NSEG)   // 128

// blocks = 16 batches x 64 grid-chunks = 1024; 512 threads = 8 waves.
// wave i handles n-segment i for all 64 grid points of the block ->
// every LDS read in the inner loop is wave-broadcast (conflict-free).
// 40 KB LDS -> 4 blocks/CU x 8 waves = 32 waves/CU (full occupancy).
__global__ __launch_bounds__(512, 8) void rkhs_embed_kernel(
    const float* __restrict__ X,   // (16,1024,2)
    const float* __restrict__ Y,   // (16,1024,8)
    float* __restrict__ out)       // [grid: 8192][Y_grid: 16*4096*9]
{
    __shared__ float sX[NPTS * 2];     // 8 KB
    __shared__ float sY[NPTS * NCH];   // 32 KB (reused for reduction)

    const int b     = blockIdx.x >> 6;   // 0..15
    const int chunk = blockIdx.x & 63;   // 0..63
    const int tid   = threadIdx.x;       // 0..511
    const int seg   = tid >> 6;          // 0..7  (== wave id)
    const int gpt   = tid & 63;          // 0..63

    // Cooperative staging, float4, coalesced.
    const float4* Xg  = (const float4*)(X + (size_t)b * NPTS * 2);
    float4*       sX4 = (float4*)sX;
    sX4[tid] = Xg[tid];                               // 2048 floats = 512 f4

    const float4* Yg  = (const float4*)(Y + (size_t)b * NPTS * NCH);
    float4*       sY4 = (float4*)sY;
#pragma unroll
    for (int i = 0; i < (NPTS * NCH / 4) / 512; ++i)  // 4 iters
        sY4[tid + 512 * i] = Yg[tid + 512 * i];

    __syncthreads();

    const int   m    = chunk * GPT + gpt;   // grid point index 0..4095
    const float step = 6.0f / 63.0f;
    const float gx   = -3.0f + (float)(m >> 6) * step;
    const float gy   = -3.0f + (float)(m & 63) * step;

    // exp(-2*d2) = exp2(C*d2), C = -2*log2(e); v_exp_f32 computes 2^x
    const float C = -2.8853900817779268f;

    float acc0 = 0.0f;
    float acc[NCH] = {0.f, 0.f, 0.f, 0.f, 0.f, 0.f, 0.f, 0.f};

    const float2* sX2 = (const float2*)sX;
    const int n0 = seg * SEGLEN;

#pragma unroll 4
    for (int k = 0; k < SEGLEN; ++k) {
        const int n = n0 + k;
        const float2 xn = sX2[n];                 // broadcast
        const float dx = gx - xn.x;
        const float dy = gy - xn.y;
        const float d2 = fmaf(dx, dx, dy * dy);
        const float w  = __builtin_amdgcn_exp2f(C * d2);   // v_exp_f32

        const float4 y0 = sY4[2 * n];             // broadcast
        const float4 y1 = sY4[2 * n + 1];

        acc0   += w;
        acc[0]  = fmaf(w, y0.x, acc[0]);
        acc[1]  = fmaf(w, y0.y, acc[1]);
        acc[2]  = fmaf(w, y0.z, acc[2]);
        acc[3]  = fmaf(w, y0.w, acc[3]);
        acc[4]  = fmaf(w, y1.x, acc[4]);
        acc[5]  = fmaf(w, y1.y, acc[5]);
        acc[6]  = fmaf(w, y1.z, acc[6]);
        acc[7]  = fmaf(w, y1.w, acc[7]);
    }

    // Cross-segment reduction: park partials in the (now dead) sY region.
    __syncthreads();                     // all waves done reading sX/sY
    float* sR = sY;                      // [seg][gpt][9] = 4608 floats (18 KB)
    {
        const int base = (seg * GPT + gpt) * 9;
        sR[base + 0] = acc0;
#pragma unroll
        for (int c = 0; c < NCH; ++c) sR[base + 1 + c] = acc[c];
    }
    __syncthreads();

    if (b == 0 && tid < GPT) {           // grid coords output (once per m)
        out[2 * m]     = gx;
        out[2 * m + 1] = gy;
    }

    if (tid < GPT) {                     // one reducer thread per grid point
        float r[9] = {0.f, 0.f, 0.f, 0.f, 0.f, 0.f, 0.f, 0.f, 0.f};
#pragma unroll
        for (int s = 0; s < NSEG; ++s) {
            const int base = (s * GPT + tid) * 9;
#pragma unroll
            for (int c = 0; c < 9; ++c) r[c] += sR[base + c];
        }
        const float inv = 1.0f / (r[0] + 1e-6f);
        float* o = out + (size_t)NGRID * 2 + ((size_t)b * NGRID + chunk * GPT + tid) * 9;
        o[0] = r[0];
#pragma unroll
        for (int c = 1; c < 9; ++c) o[c] = r[c] * inv;
    }
}

extern "C" void kernel_launch(void* const* d_in, const int* in_sizes, int n_in,
                              void* d_out, int out_size, void* d_ws, size_t ws_size,
                              hipStream_t stream) {
    const float* X = (const float*)d_in[0];   // (16,1024,2) fp32
    const float* Y = (const float*)d_in[1];   // (16,1024,8) fp32
    float* out = (float*)d_out;

    dim3 grid(NBATCH * (NGRID / GPT));        // 1024 blocks
    dim3 block(512);
    rkhs_embed_kernel<<<grid, block, 0, stream>>>(X, Y, out);
}